// Round 3
// baseline (873.505 us; speedup 1.0000x reference)
//
#include <hip/hip_runtime.h>

#define B_   32
#define T_   300
#define C1_  2312
#define O1_  512
#define O2_  512
#define O3_  10
#define M_   (B_*T_)   // 9600
#define QLEN_ 578      // C1/4 ; 4-way K split
#define NT1_  37       // ceil(578/16), last tile has 2 valid rows

// ---------------- weight prep (all f64) ----------------

__global__ void calc_f(const float* __restrict__ v, const float* __restrict__ g,
                       double* __restrict__ f, int O, int C) {
    int o = blockIdx.x;
    const float* row = v + (size_t)o * C;
    double s = 0.0;
    for (int c = threadIdx.x; c < C; c += blockDim.x) {
        double x = (double)row[c];
        s += x * x;
    }
    for (int off = 32; off; off >>= 1) s += __shfl_down(s, off);
    __shared__ double wsum[4];
    int lane = threadIdx.x & 63, wv = threadIdx.x >> 6;
    if (lane == 0) wsum[wv] = s;
    __syncthreads();
    if (threadIdx.x == 0) {
        double tot = 0.0;
        for (int i = 0; i < (int)(blockDim.x >> 6); ++i) tot += wsum[i];
        f[o] = (double)g[o] / sqrt(tot);
    }
}

// wt[c*ldo + o] = v[o*C + c] * f[o]   (double)
__global__ void transpose_scale(const float* __restrict__ v, const double* __restrict__ f,
                                double* __restrict__ wt, int O, int C, int ldo) {
    __shared__ double tile[32][33];
    int c0 = blockIdx.x * 32, o0 = blockIdx.y * 32;
    int tx = threadIdx.x, ty = threadIdx.y;
    for (int k = 0; k < 4; ++k) {
        int o = o0 + ty + k * 8, c = c0 + tx;
        double val = 0.0;
        if (o < O && c < C) val = (double)v[(size_t)o * C + c] * f[o];
        tile[ty + k * 8][tx] = val;
    }
    __syncthreads();
    for (int k = 0; k < 4; ++k) {
        int c = c0 + ty + k * 8, o = o0 + tx;
        if (c < C && o < O) wt[(size_t)c * ldo + o] = tile[tx][ty + k * 8];
    }
}

// ---------------- spike -> bitmask precompute ----------------
__global__ void build_bits(const float* __restrict__ X, unsigned* __restrict__ bits) {
    size_t idx = (size_t)blockIdx.x * 256 + threadIdx.x;
    if (idx >= (size_t)B_ * C1_ * 10) return;
    int t32 = (int)(idx % 10);
    size_t bc = idx / 10;
    const float* src = X + bc * T_ + t32 * 32;
    int nq = (t32 == 9) ? 3 : 8;   // 12 or 32 valid t's (T_=300)
    unsigned m = 0;
    for (int q = 0; q < nq; ++q) {
        float4 v = *(const float4*)(src + q * 4);
        if (v.x != 0.f) m |= 1u << (q * 4 + 0);
        if (v.y != 0.f) m |= 1u << (q * 4 + 1);
        if (v.z != 0.f) m |= 1u << (q * 4 + 2);
        if (v.w != 0.f) m |= 1u << (q * 4 + 3);
    }
    bits[idx] = m;
}

// ---------------- GEMM layer 1 v3 (f64 sparse, 4-way K-split, grid 1280) ----------------
// Grid limiter fix: 1280 blocks (5/CU, LDS-capped) so waves actually hide the
// per-tile L2-prefetch + barrier latency.  n&7 = (kq, ohalf) -> each XCD's L2
// pins ONE 1.18 MB W slice.  8 waves/block: w>>2 = b of pair, w&3 = t-octet.
// 4 atomic f64 partials per output (commutative; order-insensitivity already
// validated by the 2-way version's absmax 0.0).
__global__ __launch_bounds__(512, 4) void gemm1(const unsigned* __restrict__ Xbits,
                                                const double* __restrict__ Wt,
                                                double* __restrict__ Z) {
    __shared__ double Ws[16][256];   // 32 KB
    int n = blockIdx.x;
    int combo = n & 7;
    int kq = combo & 3;
    int o0 = (combo >> 2) * 256;
    int i = n >> 3;                      // 0..159
    int tb = i % 10;                     // 32-t window
    int bpair = i / 10;                  // 0..15
    int tid = threadIdx.x;
    int w = tid >> 6;                    // 0..7
    int lane = tid & 63;
    int b = bpair * 2 + (w >> 2);
    int w8s = __builtin_amdgcn_readfirstlane((w & 3) << 3);  // octet bit shift
    int cbeg = kq * QLEN_;
    int qend = cbeg + QLEN_;             // == C1_ for kq==3
    double acc[8][4];
#pragma unroll
    for (int tj = 0; tj < 8; ++tj)
#pragma unroll
        for (int i2 = 0; i2 < 4; ++i2) acc[tj][i2] = 0.0;
    const unsigned* xbp = Xbits + (size_t)b * C1_ * 10 + tb;

    double2 wreg[4];
    unsigned mval, mvaln = 0u;

    auto load_w = [&](int c0) {
#pragma unroll
        for (int h = 0; h < 4; ++h) {
            int idx = h * 512 + tid;
            int r = idx >> 7, od = (idx & 127) * 2;
            int c = c0 + r;
            double2 val; val.x = 0.0; val.y = 0.0;
            if (c < qend) val = *(const double2*)(Wt + (size_t)c * O1_ + o0 + od);
            wreg[h] = val;
        }
    };
    auto load_m = [&](int c0) -> unsigned {
        int c = c0 + lane;
        return (lane < 16 && c < qend) ? xbp[(size_t)c * 10] : 0u;
    };
    auto store_w = [&]() {
#pragma unroll
        for (int h = 0; h < 4; ++h) {
            int idx = h * 512 + tid;
            int r = idx >> 7, od = (idx & 127) * 2;
            *(double2*)(&Ws[r][od]) = wreg[h];
        }
    };

    load_w(cbeg);
    mval = load_m(cbeg);
    for (int tile = 0; tile < NT1_; ++tile) {
        store_w();
        __syncthreads();
        if (tile + 1 < NT1_) {
            int cn = cbeg + (tile + 1) * 16;
            load_w(cn);            // global W -> regs, overlaps inner compute
            mvaln = load_m(cn);    // next tile's masks (1 load, lanes 0..15)
        }
#pragma unroll
        for (int k = 0; k < 16; ++k) {
            unsigned smk = (unsigned)__builtin_amdgcn_readlane((int)mval, k);
            unsigned soct = (smk >> w8s) & 0xffu;
            if (soct) {   // wave-uniform scalar branch
                double wf[4];
#pragma unroll
                for (int i2 = 0; i2 < 4; ++i2) wf[i2] = Ws[k][lane + 64 * i2];
#pragma unroll
                for (int tj = 0; tj < 8; ++tj) {
                    if (soct & (1u << tj)) {
#pragma unroll
                        for (int i2 = 0; i2 < 4; ++i2) acc[tj][i2] += wf[i2];
                    }
                }
            }
        }
        mval = mvaln;
        __syncthreads();
    }
#pragma unroll
    for (int tj = 0; tj < 8; ++tj) {
        int t = tb * 32 + w8s + tj;
        if (t < T_) {
            double* dst = Z + ((size_t)b * T_ + t) * O1_ + o0;
#pragma unroll
            for (int i2 = 0; i2 < 4; ++i2)
                atomicAdd(&dst[lane + 64 * i2], acc[tj][i2]);
        }
    }
}

// ---------------- GEMM layer 2 sparse v2 (256-thr blocks, grid 640) ----------------
// Sbits: [B, 512, 10] u32 (delayed s1 spikes) ; Wt: [512, 512] f64 ; Z: plain store.
// 4 waves/block = 4 t-octets = 32 t of one b.  640 blocks (2.5/CU) vs 320:
// better latency hiding, fewer barrier participants.  c-order identical to the
// dense original => bit-identical (adding exact 0.0 is a no-op in f64).
__global__ __launch_bounds__(256, 4) void gemm2s(const unsigned* __restrict__ Sbits,
                                                 const double* __restrict__ Wt,
                                                 double* __restrict__ Z) {
    __shared__ double Ws[16][256];   // 32 KB
    int n = blockIdx.x;
    int ohalf = n & 1;
    int o0 = ohalf * 256;
    int i = n >> 1;                  // 0..319
    int tb = i % 10;                 // 32-t window
    int b = i / 10;
    int tid = threadIdx.x;
    int w = tid >> 6;                // octet 0..3
    int lane = tid & 63;
    int w8s = __builtin_amdgcn_readfirstlane(w << 3);
    double acc[8][4];
#pragma unroll
    for (int tj = 0; tj < 8; ++tj)
#pragma unroll
        for (int i2 = 0; i2 < 4; ++i2) acc[tj][i2] = 0.0;
    const unsigned* xbp = Sbits + (size_t)b * O1_ * 10 + tb;

    double2 wreg[8];
    unsigned mval, mvaln = 0u;

    auto load_w = [&](int c0) {
#pragma unroll
        for (int h = 0; h < 8; ++h) {
            int idx = h * 256 + tid;
            int r = idx >> 7, od = (idx & 127) * 2;
            int c = c0 + r;
            wreg[h] = *(const double2*)(Wt + (size_t)c * O2_ + o0 + od);
        }
    };
    auto load_m = [&](int c0) -> unsigned {
        int c = c0 + lane;
        return (lane < 16) ? xbp[(size_t)c * 10] : 0u;
    };
    auto store_w = [&]() {
#pragma unroll
        for (int h = 0; h < 8; ++h) {
            int idx = h * 256 + tid;
            int r = idx >> 7, od = (idx & 127) * 2;
            *(double2*)(&Ws[r][od]) = wreg[h];
        }
    };

    load_w(0);
    mval = load_m(0);
    for (int tile = 0; tile < 32; ++tile) {
        store_w();
        __syncthreads();
        if (tile + 1 < 32) {
            int cn = (tile + 1) * 16;
            load_w(cn);
            mvaln = load_m(cn);
        }
#pragma unroll
        for (int k = 0; k < 16; ++k) {
            unsigned smk = (unsigned)__builtin_amdgcn_readlane((int)mval, k);
            unsigned soct = (smk >> w8s) & 0xffu;
            if (soct) {
                double wf[4];
#pragma unroll
                for (int i2 = 0; i2 < 4; ++i2) wf[i2] = Ws[k][lane + 64 * i2];
#pragma unroll
                for (int tj = 0; tj < 8; ++tj) {
                    if (soct & (1u << tj)) {
#pragma unroll
                        for (int i2 = 0; i2 < 4; ++i2) acc[tj][i2] += wf[i2];
                    }
                }
            }
        }
        mval = mvaln;
        __syncthreads();
    }
#pragma unroll
    for (int tj = 0; tj < 8; ++tj) {
        int t = tb * 32 + w8s + tj;
        if (t < T_) {
            double* dst = Z + ((size_t)b * T_ + t) * O2_ + o0;
#pragma unroll
            for (int i2 = 0; i2 < 4; ++i2)
                dst[lane + 64 * i2] = acc[tj][i2];
        }
    }
}

// ---------------- GEMM layer 3 (f64 acc) ----------------
__global__ void gemm3(const float* __restrict__ A,
                      const double* __restrict__ Wt,
                      double* __restrict__ Z) {
    __shared__ double w[512 * 16];
    for (int e = threadIdx.x; e < 4096; e += 256)
        ((double2*)w)[e] = ((const double2*)Wt)[e];
    __syncthreads();
    int m = blockIdx.x * 256 + threadIdx.x;
    if (m >= M_) return;
    double acc[O3_];
#pragma unroll
    for (int o = 0; o < O3_; ++o) acc[o] = 0.0;
    const float4* Ar = (const float4*)(A + (size_t)m * 512);
    for (int cq = 0; cq < 128; ++cq) {
        float4 a = Ar[cq];
        float av[4] = {a.x, a.y, a.z, a.w};
#pragma unroll
        for (int u = 0; u < 4; ++u)
#pragma unroll
            for (int o = 0; o < O3_; ++o) acc[o] += (double)av[u] * w[(cq * 4 + u) * 16 + o];
    }
    double* dst = Z + (size_t)m * 16;
#pragma unroll
    for (int o = 0; o < O3_; ++o) dst[o] = acc[o];
}

// ---------------- LIF scan + delay, layers 1/2 (O=512, f64 state) ----------------
__global__ void scan12(const double* __restrict__ Zin,  // [B, T, 512] f64
                       const int* __restrict__ delay,   // [512]
                       float* __restrict__ Sout,        // [B, T, 512] f32 spikes
                       unsigned* __restrict__ bitsOut,  // [B, 512, 10] u32
                       float* __restrict__ sumOut) {
    int blk = blockIdx.x;
    int o = (blk & 7) * 64 + threadIdx.x;
    int b = blk >> 3;
    const double* z = Zin + (size_t)b * T_ * O1_ + o;
    float* s = Sout + (size_t)b * T_ * O1_ + o;
    unsigned* bp = bitsOut + ((size_t)b * O1_ + o) * 10;
    int d = delay[o];
    for (int t = 0; t < d; ++t) s[(size_t)t * O1_] = 0.f;
    double cur = 0.0, vol = 0.0;
    float cnt = 0.f;
    unsigned bw = 0u;   // running bit word; d<32 so words 0..8 flush in-loop
    for (int t8 = 0; t8 < 296; t8 += 8) {
        double zb[8];
#pragma unroll
        for (int u = 0; u < 8; ++u) zb[u] = z[(size_t)(t8 + u) * O1_];
#pragma unroll
        for (int u = 0; u < 8; ++u) {
            int t = t8 + u;
            cur = cur * 0.75 + zb[u];
            vol = vol * 0.97 + cur;
            float sp = (vol >= 1.25) ? 1.f : 0.f;
            if (sp > 0.f) vol = 0.0;
            int tw = t + d;
            if (tw < T_) {
                s[(size_t)tw * O1_] = sp; cnt += sp;
                if (sp > 0.f) bw |= 1u << (tw & 31);
                if ((tw & 31) == 31) { bp[tw >> 5] = bw; bw = 0u; }
            }
        }
    }
    {
        double zb[4];
#pragma unroll
        for (int u = 0; u < 4; ++u) zb[u] = z[(size_t)(296 + u) * O1_];
#pragma unroll
        for (int u = 0; u < 4; ++u) {
            int t = 296 + u;
            cur = cur * 0.75 + zb[u];
            vol = vol * 0.97 + cur;
            float sp = (vol >= 1.25) ? 1.f : 0.f;
            if (sp > 0.f) vol = 0.0;
            int tw = t + d;
            if (tw < T_) {
                s[(size_t)tw * O1_] = sp; cnt += sp;
                if (sp > 0.f) bw |= 1u << (tw & 31);
                if ((tw & 31) == 31) { bp[tw >> 5] = bw; bw = 0u; }
            }
        }
    }
    bp[9] = bw;   // word 9 never hits (tw&31)==31 within tw<300
    for (int off = 32; off; off >>= 1) cnt += __shfl_down(cnt, off);
    if (threadIdx.x == 0) atomicAdd(sumOut, cnt);
}

// ---------------- LIF scan + delay, layer 3 (O=10, f64 state) ----------------
__global__ void scan3(const double* __restrict__ Z3,  // [M, 16] f64
                      const int* __restrict__ d3,     // [10]
                      float* __restrict__ out,        // d_out: [B, 10, 300] f32
                      float* __restrict__ sumOut) {
    __shared__ double zt[T_ * 16];
    int b = blockIdx.x;
    const double2* src = (const double2*)(Z3 + (size_t)b * T_ * 16);
    for (int e = threadIdx.x; e < T_ * 8; e += 64)
        ((double2*)zt)[e] = src[e];
    __syncthreads();
    int o = threadIdx.x;
    if (o < O3_) {
        int d = d3[o];
        float* dst = out + (size_t)b * O3_ * T_ + (size_t)o * T_;
        for (int t = 0; t < d; ++t) dst[t] = 0.f;
        double cur = 0.0, vol = 0.0;
        float cnt = 0.f;
        for (int t = 0; t < T_; ++t) {
            cur = cur * 0.75 + zt[t * 16 + o];
            vol = vol * 0.97 + cur;
            float sp = (vol >= 1.25) ? 1.f : 0.f;
            if (sp > 0.f) vol = 0.0;
            int tw = t + d;
            if (tw < T_) { dst[tw] = sp; cnt += sp; }
        }
        atomicAdd(sumOut, cnt);
    }
}

__global__ void finalize(const float* __restrict__ sums, float* __restrict__ out) {
    if (threadIdx.x == 0) {
        out[0] = (float)((double)sums[0] / (double)(B_ * O1_ * T_));
        out[1] = (float)((double)sums[1] / (double)(B_ * O2_ * T_));
        out[2] = (float)((double)sums[2] / (double)(B_ * O3_ * T_));
    }
}

extern "C" void kernel_launch(void* const* d_in, const int* in_sizes, int n_in,
                              void* d_out, int out_size, void* d_ws, size_t ws_size,
                              hipStream_t stream) {
    const float* spike = (const float*)d_in[0];
    const float* v1 = (const float*)d_in[1];
    const float* g1 = (const float*)d_in[2];
    const float* v2 = (const float*)d_in[3];
    const float* g2 = (const float*)d_in[4];
    const float* v3 = (const float*)d_in[5];
    const float* g3 = (const float*)d_in[6];
    const int* d1 = (const int*)d_in[7];
    const int* d2 = (const int*)d_in[8];
    const int* d3 = (const int*)d_in[9];
    float* out = (float*)d_out;

    // Workspace: ~75 MB total.
    double* dw = (double*)d_ws;
    size_t off = 0;
    double* f1  = dw + off; off += 512;
    double* f2  = dw + off; off += 512;
    double* f3  = dw + off; off += 16;
    double* Wt1 = dw + off; off += (size_t)C1_ * O1_;
    double* Wt2 = dw + off; off += 512 * 512;
    double* Wt3 = dw + off; off += 512 * 16;
    double* zA  = dw + off; off += (size_t)M_ * 512;
    double* z3b = dw + off; off += (size_t)M_ * 16;
    float* fw = (float*)(dw + off);
    float* sB    = fw;                                   // f32 spikes, M*512
    float* sums  = fw + (size_t)M_ * 512;                // 4 floats
    unsigned* Xbits = (unsigned*)(fw + (size_t)M_ * 512 + 4);  // B*C1*10 u32
    unsigned* bits2 = Xbits + (size_t)B_ * C1_ * 10;           // B*512*10 u32
    (void)ws_size; (void)out_size; (void)in_sizes; (void)n_in;

    hipMemsetAsync(sums, 0, 4 * sizeof(float), stream);
    hipMemsetAsync(zA, 0, (size_t)M_ * 512 * sizeof(double), stream);  // K-split atomics

    build_bits<<<(B_ * C1_ * 10 + 255) / 256, 256, 0, stream>>>(spike, Xbits);

    calc_f<<<512, 256, 0, stream>>>(v1, g1, f1, O1_, C1_);
    calc_f<<<512, 256, 0, stream>>>(v2, g2, f2, O2_, O1_);
    calc_f<<<O3_, 256, 0, stream>>>(v3, g3, f3, O3_, O2_);

    transpose_scale<<<dim3((C1_ + 31) / 32, 16), dim3(32, 8), 0, stream>>>(v1, f1, Wt1, O1_, C1_, O1_);
    transpose_scale<<<dim3(16, 16), dim3(32, 8), 0, stream>>>(v2, f2, Wt2, O2_, O1_, O2_);
    transpose_scale<<<dim3(16, 1), dim3(32, 8), 0, stream>>>(v3, f3, Wt3, O3_, O2_, 16);

    // gemm1 v3: 1280 blocks x 512 thr; n&7 = (kq, ohalf) keeps XCD L2 pinning
    gemm1<<<1280, 512, 0, stream>>>(Xbits, Wt1, zA);                  // zA += z1
    scan12<<<256, 64, 0, stream>>>(zA, d1, sB, bits2, sums + 0);      // sB,bits2 = s1
    gemm2s<<<640, 256, 0, stream>>>(bits2, Wt2, zA);                  // zA = z2 (sparse)
    scan12<<<256, 64, 0, stream>>>(zA, d2, sB, bits2, sums + 1);      // sB = s2
    gemm3<<<(M_ + 255) / 256, 256, 0, stream>>>(sB, Wt3, z3b);        // z3b = z3
    scan3<<<B_, 64, 0, stream>>>(z3b, d3, out, sums + 2);
    finalize<<<1, 64, 0, stream>>>(sums, out + (size_t)B_ * O3_ * T_);
}

// Round 4
// 794.098 us; speedup vs baseline: 1.1000x; 1.1000x over previous
//
#include <hip/hip_runtime.h>

#define B_   32
#define T_   300
#define C1_  2312
#define O1_  512
#define O2_  512
#define O3_  10
#define M_   (B_*T_)   // 9600
#define KSPLIT_ 1152   // gemm1 K halves: [0,1152) = 72 tiles, [1152,2312) = 73 tiles

// ---------------- weight prep (all f64) ----------------

__global__ void calc_f(const float* __restrict__ v, const float* __restrict__ g,
                       double* __restrict__ f, int O, int C) {
    int o = blockIdx.x;
    const float* row = v + (size_t)o * C;
    double s = 0.0;
    for (int c = threadIdx.x; c < C; c += blockDim.x) {
        double x = (double)row[c];
        s += x * x;
    }
    for (int off = 32; off; off >>= 1) s += __shfl_down(s, off);
    __shared__ double wsum[4];
    int lane = threadIdx.x & 63, wv = threadIdx.x >> 6;
    if (lane == 0) wsum[wv] = s;
    __syncthreads();
    if (threadIdx.x == 0) {
        double tot = 0.0;
        for (int i = 0; i < (int)(blockDim.x >> 6); ++i) tot += wsum[i];
        f[o] = (double)g[o] / sqrt(tot);
    }
}

// wt[c*ldo + o] = v[o*C + c] * f[o]   (double)
__global__ void transpose_scale(const float* __restrict__ v, const double* __restrict__ f,
                                double* __restrict__ wt, int O, int C, int ldo) {
    __shared__ double tile[32][33];
    int c0 = blockIdx.x * 32, o0 = blockIdx.y * 32;
    int tx = threadIdx.x, ty = threadIdx.y;
    for (int k = 0; k < 4; ++k) {
        int o = o0 + ty + k * 8, c = c0 + tx;
        double val = 0.0;
        if (o < O && c < C) val = (double)v[(size_t)o * C + c] * f[o];
        tile[ty + k * 8][tx] = val;
    }
    __syncthreads();
    for (int k = 0; k < 4; ++k) {
        int c = c0 + ty + k * 8, o = o0 + tx;
        if (c < C && o < O) wt[(size_t)c * ldo + o] = tile[tx][ty + k * 8];
    }
}

// ---------------- spike -> bitmask precompute ----------------
__global__ void build_bits(const float* __restrict__ X, unsigned* __restrict__ bits) {
    size_t idx = (size_t)blockIdx.x * 256 + threadIdx.x;
    if (idx >= (size_t)B_ * C1_ * 10) return;
    int t32 = (int)(idx % 10);
    size_t bc = idx / 10;
    const float* src = X + bc * T_ + t32 * 32;
    int nq = (t32 == 9) ? 3 : 8;   // 12 or 32 valid t's (T_=300)
    unsigned m = 0;
    for (int q = 0; q < nq; ++q) {
        float4 v = *(const float4*)(src + q * 4);
        if (v.x != 0.f) m |= 1u << (q * 4 + 0);
        if (v.y != 0.f) m |= 1u << (q * 4 + 1);
        if (v.z != 0.f) m |= 1u << (q * 4 + 2);
        if (v.w != 0.f) m |= 1u << (q * 4 + 3);
    }
    bits[idx] = m;
}

// ---------------- GEMM layer 1 v4 (f64 sparse, LDS dbuf 1-barrier, plain K-partials) ----------------
// Round-3 evidence: occupancy stuck ~12 waves/CU with blocks to spare -> the
// 2-barrier lockstep was the limiter, and 153.6 MB of atomic RMW was overhead.
// v4: Ws[2] double-buffer (64 KB, 2 blocks/CU = 16 waves/CU), ONE barrier per
// tile (store to buf^1 after compute of buf; reads of buf^1 finished before
// the PREVIOUS barrier => race-free).  K=2 halves write PLAIN stores to two
// partial buffers Z0/Z1; scan12 sums them in fixed order (no atomics, no memset).
// n&3 = (khalf, ohalf): each XCD (n&7) still sees ONE 2.37 MB W slice in L2.
__global__ __launch_bounds__(512, 4) void gemm1(const unsigned* __restrict__ Xbits,
                                                const double* __restrict__ Wt,
                                                double* __restrict__ Z0,
                                                double* __restrict__ Z1) {
    __shared__ double Ws[2][16][256];   // 64 KB double-buffer
    int n = blockIdx.x;
    int combo = n & 3;
    int khalf = combo & 1;
    int o0 = (combo >> 1) * 256;
    int i = n >> 2;                      // 0..159
    int tb = i % 10;                     // 32-t window
    int bpair = i / 10;                  // 0..15
    int tid = threadIdx.x;
    int w = tid >> 6;                    // 0..7
    int lane = tid & 63;
    int b = bpair * 2 + (w >> 2);
    int w8s = __builtin_amdgcn_readfirstlane((w & 3) << 3);  // octet bit shift
    int cbeg = khalf ? KSPLIT_ : 0;
    int qend = khalf ? C1_ : KSPLIT_;
    const int NT = khalf ? 73 : 72;
    double* __restrict__ Z = khalf ? Z1 : Z0;
    double acc[8][4];
#pragma unroll
    for (int tj = 0; tj < 8; ++tj)
#pragma unroll
        for (int i2 = 0; i2 < 4; ++i2) acc[tj][i2] = 0.0;
    const unsigned* xbp = Xbits + (size_t)b * C1_ * 10 + tb;

    double2 wreg[4];
    unsigned mval, mvaln = 0u;

    auto load_w = [&](int c0) {
#pragma unroll
        for (int h = 0; h < 4; ++h) {
            int idx = h * 512 + tid;
            int r = idx >> 7, od = (idx & 127) * 2;
            int c = c0 + r;
            double2 val; val.x = 0.0; val.y = 0.0;
            if (c < qend) val = *(const double2*)(Wt + (size_t)c * O1_ + o0 + od);
            wreg[h] = val;
        }
    };
    auto load_m = [&](int c0) -> unsigned {
        int c = c0 + lane;
        return (lane < 16 && c < qend) ? xbp[(size_t)c * 10] : 0u;
    };
    auto store_w = [&](int bi) {
#pragma unroll
        for (int h = 0; h < 4; ++h) {
            int idx = h * 512 + tid;
            int r = idx >> 7, od = (idx & 127) * 2;
            *(double2*)(&Ws[bi][r][od]) = wreg[h];
        }
    };

    load_w(cbeg);
    mval = load_m(cbeg);
    store_w(0);
    __syncthreads();
    int cur = 0;
    for (int tile = 0; tile < NT; ++tile) {
        if (tile + 1 < NT) {
            int cn = cbeg + (tile + 1) * 16;
            load_w(cn);            // prefetch next tile into regs (covered by compute)
            mvaln = load_m(cn);
        }
#pragma unroll
        for (int k = 0; k < 16; ++k) {
            unsigned smk = (unsigned)__builtin_amdgcn_readlane((int)mval, k);
            unsigned soct = (smk >> w8s) & 0xffu;
            if (soct) {   // wave-uniform scalar branch
                double wf[4];
#pragma unroll
                for (int i2 = 0; i2 < 4; ++i2) wf[i2] = Ws[cur][k][lane + 64 * i2];
#pragma unroll
                for (int tj = 0; tj < 8; ++tj) {
                    if (soct & (1u << tj)) {
#pragma unroll
                        for (int i2 = 0; i2 < 4; ++i2) acc[tj][i2] += wf[i2];
                    }
                }
            }
        }
        if (tile + 1 < NT) {
            store_w(cur ^ 1);      // other buffer: prior reads of it ended before last barrier
            __syncthreads();       // ONE barrier per tile
        }
        mval = mvaln;
        cur ^= 1;
    }
#pragma unroll
    for (int tj = 0; tj < 8; ++tj) {
        int t = tb * 32 + w8s + tj;
        if (t < T_) {
            double* dst = Z + ((size_t)b * T_ + t) * O1_ + o0;
#pragma unroll
            for (int i2 = 0; i2 < 4; ++i2)
                dst[lane + 64 * i2] = acc[tj][i2];   // plain store (K-partial)
        }
    }
}

// ---------------- GEMM layer 2 sparse v3 (512-thr, dbuf 1-barrier, K=2 partials) ----------------
// Sbits: [B, 512, 10] u32 (delayed s1 spikes) ; Wt: [512, 512] f64.
// Round-2 512-thr shape (measured cheaper than round-3 256-thr) + the same
// dbuf/partial-store structure as gemm1.  Grid 640 = 32b x 5 twin x 2 ohalf x
// 2 khalf -> 2 blocks/CU resident (64 KB LDS).  scan12 sums Z0+Z1 (c-halves
// [0,256)+[256,512)) in fixed order.
__global__ __launch_bounds__(512, 4) void gemm2s(const unsigned* __restrict__ Sbits,
                                                 const double* __restrict__ Wt,
                                                 double* __restrict__ Z0,
                                                 double* __restrict__ Z1) {
    __shared__ double Ws[2][16][256];   // 64 KB
    int n = blockIdx.x;
    int combo = n & 3;
    int khalf = combo & 1;
    int o0 = (combo >> 1) * 256;
    int i = n >> 2;                  // 0..159
    int twin = i % 5;                // 64-t window
    int b = i / 5;
    int tid = threadIdx.x;
    int w = tid >> 6;                // 0..7
    int lane = tid & 63;
    int w8s = __builtin_amdgcn_readfirstlane((w & 3) << 3);
    int word = twin * 2 + (w >> 2);  // which u32 of the 10 holds this octet
    int cbeg = khalf * 256;
    double* __restrict__ Z = khalf ? Z1 : Z0;
    double acc[8][4];
#pragma unroll
    for (int tj = 0; tj < 8; ++tj)
#pragma unroll
        for (int i2 = 0; i2 < 4; ++i2) acc[tj][i2] = 0.0;
    const unsigned* xbp = Sbits + (size_t)b * O1_ * 10 + word;

    double2 wreg[4];
    unsigned mval, mvaln = 0u;

    auto load_w = [&](int c0) {
#pragma unroll
        for (int h = 0; h < 4; ++h) {
            int idx = h * 512 + tid;
            int r = idx >> 7, od = (idx & 127) * 2;
            int c = c0 + r;
            wreg[h] = *(const double2*)(Wt + (size_t)c * O2_ + o0 + od);
        }
    };
    auto load_m = [&](int c0) -> unsigned {
        int c = c0 + lane;
        return (lane < 16) ? xbp[(size_t)c * 10] : 0u;
    };
    auto store_w = [&](int bi) {
#pragma unroll
        for (int h = 0; h < 4; ++h) {
            int idx = h * 512 + tid;
            int r = idx >> 7, od = (idx & 127) * 2;
            *(double2*)(&Ws[bi][r][od]) = wreg[h];
        }
    };

    load_w(cbeg);
    mval = load_m(cbeg);
    store_w(0);
    __syncthreads();
    int cur = 0;
    for (int tile = 0; tile < 16; ++tile) {
        if (tile + 1 < 16) {
            int cn = cbeg + (tile + 1) * 16;
            load_w(cn);
            mvaln = load_m(cn);
        }
#pragma unroll
        for (int k = 0; k < 16; ++k) {
            unsigned smk = (unsigned)__builtin_amdgcn_readlane((int)mval, k);
            unsigned soct = (smk >> w8s) & 0xffu;
            if (soct) {
                double wf[4];
#pragma unroll
                for (int i2 = 0; i2 < 4; ++i2) wf[i2] = Ws[cur][k][lane + 64 * i2];
#pragma unroll
                for (int tj = 0; tj < 8; ++tj) {
                    if (soct & (1u << tj)) {
#pragma unroll
                        for (int i2 = 0; i2 < 4; ++i2) acc[tj][i2] += wf[i2];
                    }
                }
            }
        }
        if (tile + 1 < 16) {
            store_w(cur ^ 1);
            __syncthreads();
        }
        mval = mvaln;
        cur ^= 1;
    }
#pragma unroll
    for (int tj = 0; tj < 8; ++tj) {
        int t = twin * 64 + w * 8 + tj;
        if (t < T_) {
            double* dst = Z + ((size_t)b * T_ + t) * O2_ + o0;
#pragma unroll
            for (int i2 = 0; i2 < 4; ++i2)
                dst[lane + 64 * i2] = acc[tj][i2];
        }
    }
}

// ---------------- GEMM layer 3 (f64 acc) ----------------
__global__ void gemm3(const float* __restrict__ A,
                      const double* __restrict__ Wt,
                      double* __restrict__ Z) {
    __shared__ double w[512 * 16];
    for (int e = threadIdx.x; e < 4096; e += 256)
        ((double2*)w)[e] = ((const double2*)Wt)[e];
    __syncthreads();
    int m = blockIdx.x * 256 + threadIdx.x;
    if (m >= M_) return;
    double acc[O3_];
#pragma unroll
    for (int o = 0; o < O3_; ++o) acc[o] = 0.0;
    const float4* Ar = (const float4*)(A + (size_t)m * 512);
    for (int cq = 0; cq < 128; ++cq) {
        float4 a = Ar[cq];
        float av[4] = {a.x, a.y, a.z, a.w};
#pragma unroll
        for (int u = 0; u < 4; ++u)
#pragma unroll
            for (int o = 0; o < O3_; ++o) acc[o] += (double)av[u] * w[(cq * 4 + u) * 16 + o];
    }
    double* dst = Z + (size_t)m * 16;
#pragma unroll
    for (int o = 0; o < O3_; ++o) dst[o] = acc[o];
}

// ---------------- LIF scan + delay, layers 1/2 (O=512, f64 state) ----------------
// Zb (2nd K-partial) summed in fixed order if non-null.  Sout / bitsOut each
// optional (layer 1 needs only bits; layer 2 needs only floats).
__global__ void scan12(const double* __restrict__ Za,   // [B, T, 512] f64
                       const double* __restrict__ Zb,   // partial 2 or nullptr
                       const int* __restrict__ delay,   // [512]
                       float* __restrict__ Sout,        // [B, T, 512] f32 or nullptr
                       unsigned* __restrict__ bitsOut,  // [B, 512, 10] u32 or nullptr
                       float* __restrict__ sumOut) {
    int blk = blockIdx.x;
    int o = (blk & 7) * 64 + threadIdx.x;
    int b = blk >> 3;
    size_t base = (size_t)b * T_ * O1_ + o;
    const double* z  = Za + base;
    const double* z2 = Zb ? Zb + base : nullptr;
    float* s = Sout ? Sout + base : nullptr;
    int d = delay[o];
    if (s) for (int t = 0; t < d; ++t) s[(size_t)t * O1_] = 0.f;
    double cur = 0.0, vol = 0.0;
    float cnt = 0.f;
    unsigned bw = 0u;   // running bit word; d<32 so words 0..8 flush in-loop
    for (int t8 = 0; t8 < 296; t8 += 8) {
        double zbuf[8];
#pragma unroll
        for (int u = 0; u < 8; ++u) zbuf[u] = z[(size_t)(t8 + u) * O1_];
        if (z2) {
#pragma unroll
            for (int u = 0; u < 8; ++u) zbuf[u] += z2[(size_t)(t8 + u) * O1_];
        }
#pragma unroll
        for (int u = 0; u < 8; ++u) {
            int t = t8 + u;
            cur = cur * 0.75 + zbuf[u];
            vol = vol * 0.97 + cur;
            float sp = (vol >= 1.25) ? 1.f : 0.f;
            if (sp > 0.f) vol = 0.0;
            int tw = t + d;
            if (tw < T_) {
                if (s) s[(size_t)tw * O1_] = sp;
                cnt += sp;
                if (bitsOut) {
                    if (sp > 0.f) bw |= 1u << (tw & 31);
                    if ((tw & 31) == 31) { bitsOut[((size_t)b * O1_ + o) * 10 + (tw >> 5)] = bw; bw = 0u; }
                }
            }
        }
    }
    {
        double zbuf[4];
#pragma unroll
        for (int u = 0; u < 4; ++u) zbuf[u] = z[(size_t)(296 + u) * O1_];
        if (z2) {
#pragma unroll
            for (int u = 0; u < 4; ++u) zbuf[u] += z2[(size_t)(296 + u) * O1_];
        }
#pragma unroll
        for (int u = 0; u < 4; ++u) {
            int t = 296 + u;
            cur = cur * 0.75 + zbuf[u];
            vol = vol * 0.97 + cur;
            float sp = (vol >= 1.25) ? 1.f : 0.f;
            if (sp > 0.f) vol = 0.0;
            int tw = t + d;
            if (tw < T_) {
                if (s) s[(size_t)tw * O1_] = sp;
                cnt += sp;
                if (bitsOut) {
                    if (sp > 0.f) bw |= 1u << (tw & 31);
                    if ((tw & 31) == 31) { bitsOut[((size_t)b * O1_ + o) * 10 + (tw >> 5)] = bw; bw = 0u; }
                }
            }
        }
    }
    if (bitsOut) bitsOut[((size_t)b * O1_ + o) * 10 + 9] = bw;  // word 9 never flushes in-loop
    for (int off = 32; off; off >>= 1) cnt += __shfl_down(cnt, off);
    if (threadIdx.x == 0) atomicAdd(sumOut, cnt);
}

// ---------------- LIF scan + delay, layer 3 (O=10, f64 state) ----------------
__global__ void scan3(const double* __restrict__ Z3,  // [M, 16] f64
                      const int* __restrict__ d3,     // [10]
                      float* __restrict__ out,        // d_out: [B, 10, 300] f32
                      float* __restrict__ sumOut) {
    __shared__ double zt[T_ * 16];
    int b = blockIdx.x;
    const double2* src = (const double2*)(Z3 + (size_t)b * T_ * 16);
    for (int e = threadIdx.x; e < T_ * 8; e += 64)
        ((double2*)zt)[e] = src[e];
    __syncthreads();
    int o = threadIdx.x;
    if (o < O3_) {
        int d = d3[o];
        float* dst = out + (size_t)b * O3_ * T_ + (size_t)o * T_;
        for (int t = 0; t < d; ++t) dst[t] = 0.f;
        double cur = 0.0, vol = 0.0;
        float cnt = 0.f;
        for (int t = 0; t < T_; ++t) {
            cur = cur * 0.75 + zt[t * 16 + o];
            vol = vol * 0.97 + cur;
            float sp = (vol >= 1.25) ? 1.f : 0.f;
            if (sp > 0.f) vol = 0.0;
            int tw = t + d;
            if (tw < T_) { dst[tw] = sp; cnt += sp; }
        }
        atomicAdd(sumOut, cnt);
    }
}

__global__ void finalize(const float* __restrict__ sums, float* __restrict__ out) {
    if (threadIdx.x == 0) {
        out[0] = (float)((double)sums[0] / (double)(B_ * O1_ * T_));
        out[1] = (float)((double)sums[1] / (double)(B_ * O2_ * T_));
        out[2] = (float)((double)sums[2] / (double)(B_ * O3_ * T_));
    }
}

extern "C" void kernel_launch(void* const* d_in, const int* in_sizes, int n_in,
                              void* d_out, int out_size, void* d_ws, size_t ws_size,
                              hipStream_t stream) {
    const float* spike = (const float*)d_in[0];
    const float* v1 = (const float*)d_in[1];
    const float* g1 = (const float*)d_in[2];
    const float* v2 = (const float*)d_in[3];
    const float* g2 = (const float*)d_in[4];
    const float* v3 = (const float*)d_in[5];
    const float* g3 = (const float*)d_in[6];
    const int* d1 = (const int*)d_in[7];
    const int* d2 = (const int*)d_in[8];
    const int* d3 = (const int*)d_in[9];
    float* out = (float*)d_out;

    // Workspace: ~115 MB (adds second 39 MB K-partial buffer zB).
    double* dw = (double*)d_ws;
    size_t off = 0;
    double* f1  = dw + off; off += 512;
    double* f2  = dw + off; off += 512;
    double* f3  = dw + off; off += 16;
    double* Wt1 = dw + off; off += (size_t)C1_ * O1_;
    double* Wt2 = dw + off; off += 512 * 512;
    double* Wt3 = dw + off; off += 512 * 16;
    double* zA  = dw + off; off += (size_t)M_ * 512;
    double* zB  = dw + off; off += (size_t)M_ * 512;
    double* z3b = dw + off; off += (size_t)M_ * 16;
    float* fw = (float*)(dw + off);
    float* sB    = fw;                                   // f32 spikes, M*512
    float* sums  = fw + (size_t)M_ * 512;                // 4 floats
    unsigned* Xbits = (unsigned*)(fw + (size_t)M_ * 512 + 4);  // B*C1*10 u32
    unsigned* bits2 = Xbits + (size_t)B_ * C1_ * 10;           // B*512*10 u32
    (void)ws_size; (void)out_size; (void)in_sizes; (void)n_in;

    hipMemsetAsync(sums, 0, 4 * sizeof(float), stream);
    // no zA memset needed: K-partials are written unconditionally (plain stores)

    build_bits<<<(B_ * C1_ * 10 + 255) / 256, 256, 0, stream>>>(spike, Xbits);

    calc_f<<<512, 256, 0, stream>>>(v1, g1, f1, O1_, C1_);
    calc_f<<<512, 256, 0, stream>>>(v2, g2, f2, O2_, O1_);
    calc_f<<<O3_, 256, 0, stream>>>(v3, g3, f3, O3_, O2_);

    transpose_scale<<<dim3((C1_ + 31) / 32, 16), dim3(32, 8), 0, stream>>>(v1, f1, Wt1, O1_, C1_, O1_);
    transpose_scale<<<dim3(16, 16), dim3(32, 8), 0, stream>>>(v2, f2, Wt2, O2_, O1_, O2_);
    transpose_scale<<<dim3(16, 1), dim3(32, 8), 0, stream>>>(v3, f3, Wt3, O3_, O2_, 16);

    // gemm1 v4: 640 blocks x 512 thr, dbuf 1-barrier, K=2 plain partials
    gemm1<<<640, 512, 0, stream>>>(Xbits, Wt1, zA, zB);
    // scan12 #1: sum zA+zB, emit ONLY bits (s1 floats are dead)
    scan12<<<256, 64, 0, stream>>>(zA, zB, d1, nullptr, bits2, sums + 0);
    // gemm2s v3: 640 blocks x 512 thr, dbuf, K=2 plain partials
    gemm2s<<<640, 512, 0, stream>>>(bits2, Wt2, zA, zB);
    // scan12 #2: sum zA+zB, emit ONLY floats (bits are dead)
    scan12<<<256, 64, 0, stream>>>(zA, zB, d2, sB, nullptr, sums + 1);
    gemm3<<<(M_ + 255) / 256, 256, 0, stream>>>(sB, Wt3, z3b);        // z3b = z3
    scan3<<<B_, 64, 0, stream>>>(z3b, d3, out, sums + 2);
    finalize<<<1, 64, 0, stream>>>(sums, out + (size_t)B_ * O3_ * T_);
}